// Round 1
// baseline (980.630 us; speedup 1.0000x reference)
//
#include <hip/hip_runtime.h>

#define N_SRC   100000
#define N_DST   100000
#define N_EDGES 1250000
#define D_FEAT  64
#define HIDDEN  64
#define OUT_F   128

// ---------------------------------------------------------------------------
// Kernel 1: hs = relu(h_src @ W1 + b1)   [N_SRC, 64]
// One wave per row: lane j computes output j. W1 staged in LDS (16 KB).
// Input row held one-element-per-lane, broadcast via __shfl.
// ---------------------------------------------------------------------------
__global__ __launch_bounds__(256) void fc1_kernel(
        const float* __restrict__ h_src, const float* __restrict__ W1,
        const float* __restrict__ b1, float* __restrict__ hs) {
    __shared__ float W1s[D_FEAT * HIDDEN];
    for (int i = threadIdx.x; i < D_FEAT * HIDDEN; i += 256) W1s[i] = W1[i];
    __syncthreads();
    const int lane = threadIdx.x & 63;
    const int wid  = threadIdx.x >> 6;
    const int row  = blockIdx.x * 4 + wid;
    if (row >= N_SRC) return;
    float x   = h_src[row * D_FEAT + lane];
    float acc = b1[lane];
    #pragma unroll
    for (int k = 0; k < D_FEAT; ++k) {
        float a = __shfl(x, k, 64);
        acc = fmaf(a, W1s[k * HIDDEN + lane], acc);
    }
    hs[row * HIDDEN + lane] = fmaxf(acc, 0.0f);
}

// ---------------------------------------------------------------------------
// Kernel 2: edge scatter.  One wave per edge (grid-stride).
// lane k: vs[dst][k] += hs[src][k] * w   (coalesced 256B gather + atomics)
// lane 0: wsum[dst] += w
// ---------------------------------------------------------------------------
__global__ __launch_bounds__(256) void edge_kernel(
        const float* __restrict__ hs, const float* __restrict__ ew,
        const int* __restrict__ src, const int* __restrict__ dst,
        float* __restrict__ vs, float* __restrict__ wsum) {
    const int lane = threadIdx.x & 63;
    const int wid  = blockIdx.x * 4 + (threadIdx.x >> 6);
    const int stride = gridDim.x * 4;
    for (int e = wid; e < N_EDGES; e += stride) {
        int   s = src[e];
        int   d = dst[e];
        float w = ew[e];
        float val = hs[s * HIDDEN + lane] * w;
        atomicAdd(&vs[d * HIDDEN + lane], val);
        if (lane == 0) atomicAdd(&wsum[d], w);
    }
}

// ---------------------------------------------------------------------------
// Kernel 3: new = relu(concat([vs/max(wsum,1), h_dst]) @ W2 + b2)
// W2 (128x128 f32 = 64 KB) in LDS. One wave handles 4 rows, 2 outputs/lane
// (j = lane, lane+64). Weight LDS reads amortized over the 4 rows.
// Accumulates global sum-of-squares in double (one atomicAdd per wave).
// ---------------------------------------------------------------------------
__global__ __launch_bounds__(256) void fc2_kernel(
        const float* __restrict__ vs, const float* __restrict__ wsum,
        const float* __restrict__ h_dst, const float* __restrict__ W2,
        const float* __restrict__ b2, float* __restrict__ out,
        double* __restrict__ sumsq) {
    __shared__ float W2s[(HIDDEN + D_FEAT) * OUT_F];   // 64 KiB exactly
    for (int i = threadIdx.x; i < (HIDDEN + D_FEAT) * OUT_F; i += 256) W2s[i] = W2[i];
    __syncthreads();
    const int lane = threadIdx.x & 63;
    const int wid  = threadIdx.x >> 6;
    const float b2a = b2[lane];
    const float b2b = b2[lane + 64];
    double ss = 0.0;
    const int rowStride = gridDim.x * 4 * 4;           // waves * 4 rows each
    for (int base = (blockIdx.x * 4 + wid) * 4; base < N_DST; base += rowStride) {
        const int nr = min(4, N_DST - base);
        float x0[4], x1[4], acc0[4], acc1[4];
        #pragma unroll
        for (int r = 0; r < 4; ++r) {
            int row = base + (r < nr ? r : 0);         // clamp; clamped results discarded
            float winv = 1.0f / fmaxf(wsum[row], 1.0f);
            x0[r] = vs[row * HIDDEN + lane] * winv;
            x1[r] = h_dst[row * D_FEAT + lane];
            acc0[r] = b2a;
            acc1[r] = b2b;
        }
        #pragma unroll
        for (int k = 0; k < HIDDEN; ++k) {
            float wA = W2s[k * OUT_F + lane];
            float wB = W2s[k * OUT_F + 64 + lane];
            #pragma unroll
            for (int r = 0; r < 4; ++r) {
                float a = __shfl(x0[r], k, 64);
                acc0[r] = fmaf(a, wA, acc0[r]);
                acc1[r] = fmaf(a, wB, acc1[r]);
            }
        }
        #pragma unroll
        for (int k = 0; k < D_FEAT; ++k) {
            float wA = W2s[(HIDDEN + k) * OUT_F + lane];
            float wB = W2s[(HIDDEN + k) * OUT_F + 64 + lane];
            #pragma unroll
            for (int r = 0; r < 4; ++r) {
                float a = __shfl(x1[r], k, 64);
                acc0[r] = fmaf(a, wA, acc0[r]);
                acc1[r] = fmaf(a, wB, acc1[r]);
            }
        }
        #pragma unroll
        for (int r = 0; r < 4; ++r) {
            if (r < nr) {
                float v0 = fmaxf(acc0[r], 0.0f);
                float v1 = fmaxf(acc1[r], 0.0f);
                int row = base + r;
                out[row * OUT_F + lane]      = v0;
                out[row * OUT_F + 64 + lane] = v1;
                ss += (double)v0 * v0 + (double)v1 * v1;
            }
        }
    }
    #pragma unroll
    for (int off = 32; off > 0; off >>= 1) ss += __shfl_down(ss, off, 64);
    if (lane == 0) atomicAdd(sumsq, ss);
}

// ---------------------------------------------------------------------------
// Kernel 4: out *= 1/sqrt(sumsq)   (in-place, float4 grid-stride)
// ---------------------------------------------------------------------------
__global__ __launch_bounds__(256) void scale_kernel(
        float* __restrict__ out, const double* __restrict__ sumsq, int n4) {
    const float s = (float)(1.0 / sqrt(*sumsq));
    float4* o4 = (float4*)out;
    const int stride = gridDim.x * blockDim.x;
    for (int i = blockIdx.x * blockDim.x + threadIdx.x; i < n4; i += stride) {
        float4 v = o4[i];
        v.x *= s; v.y *= s; v.z *= s; v.w *= s;
        o4[i] = v;
    }
}

extern "C" void kernel_launch(void* const* d_in, const int* in_sizes, int n_in,
                              void* d_out, int out_size, void* d_ws, size_t ws_size,
                              hipStream_t stream) {
    const float* h_src = (const float*)d_in[0];
    const float* h_dst = (const float*)d_in[1];
    const float* ew    = (const float*)d_in[2];
    const float* W1    = (const float*)d_in[3];
    const float* b1    = (const float*)d_in[4];
    const float* W2    = (const float*)d_in[5];
    const float* b2    = (const float*)d_in[6];
    const int*   src   = (const int*)d_in[7];
    const int*   dst   = (const int*)d_in[8];
    float* out = (float*)d_out;

    // Scratch layout:
    //   d_out[0 .. 6.4M floats)  : hs (reused; fc2 overwrites all of d_out later)
    //   d_ws + 0                 : vs    [N_DST * 64] f32   (25.6 MB)
    //   d_ws + 25,600,000        : wsum  [N_DST]      f32   (0.4 MB)
    //   d_ws + 26,000,000        : sumsq [1]          f64
    float*  hs    = out;
    float*  vs    = (float*)d_ws;
    float*  wsum  = (float*)((char*)d_ws + (size_t)N_DST * HIDDEN * 4);
    double* sumsq = (double*)((char*)d_ws + (size_t)N_DST * HIDDEN * 4 + (size_t)N_DST * 4);

    hipMemsetAsync(d_ws, 0, (size_t)N_DST * HIDDEN * 4 + (size_t)N_DST * 4 + 8, stream);

    fc1_kernel<<<(N_SRC + 3) / 4, 256, 0, stream>>>(h_src, W1, b1, hs);
    edge_kernel<<<4096, 256, 0, stream>>>(hs, ew, src, dst, vs, wsum);
    fc2_kernel<<<1024, 256, 0, stream>>>(vs, wsum, h_dst, W2, b2, out, sumsq);
    scale_kernel<<<2048, 256, 0, stream>>>(out, sumsq, N_DST * OUT_F / 4);
}